// Round 5
// baseline (177.824 us; speedup 1.0000x reference)
//
#include <hip/hip_runtime.h>

// Problem constants (hardcoded from reference):
//   T=4096, D_MODEL=1024, N_HEADS=16, HEAD_DIM=64, ROT=32, PAIR=16,
//   EPS=1e-6, SCALE=0.12, WINDOW=1024. tokens/pos/block_size unused.
//
// Attention numerics: rmsnorm => ||q||=||k||=8, so |q.k|*SCALE <= 7.68 ->
// exp bounded [4.6e-4, 2164]: softmax max-subtraction unnecessary.
// SCALE*log2(e) pre-folded into Q at the gemm_qkv epilogue: p = exp2(z).
//
// R5 changes (attn only; clean attribution):
//  - Raw s_barrier + ROLE-SPLIT counted vmcnt (T4): __syncthreads drained
//    vmcnt(0) in ALL waves at BOTH barriers, exposing K(n+1)'s L2 latency
//    (issued ~1 QK-phase earlier) to the whole block every tile. Now:
//    barrier1 (publishes V(n)): only V-staging waves (4-7) drain vmcnt --
//    covered by QK(h0). barrier2 (publishes K(n+1)): only K-staging waves
//    (0-3) drain -- covered by the full tile (QK+2PV, ~3x longer).
//    sched_barrier(0) after each barrier blocks LDS-read hoisting.
//  - R4 structure otherwise unchanged: 128-key tiles, K dbuf + early-V,
//    per-half dead/clean skip, setprio around PV.

typedef __bf16 bf16x8 __attribute__((ext_vector_type(8)));
typedef __bf16 bf16x2 __attribute__((ext_vector_type(2)));
typedef float f32x4 __attribute__((ext_vector_type(4)));
typedef unsigned short u16x8 __attribute__((ext_vector_type(8)));
typedef unsigned short u16x4 __attribute__((ext_vector_type(4)));

#define MFMA16(a, b, c) __builtin_amdgcn_mfma_f32_16x16x32_bf16((a), (b), (c), 0, 0, 0)

__device__ __forceinline__ unsigned short f2bf(float f) {
    unsigned int u = __float_as_uint(f);
    u += 0x7fffu + ((u >> 16) & 1u);   // round-to-nearest-even
    return (unsigned short)(u >> 16);
}
__device__ __forceinline__ float bf2f(unsigned short h) {
    return __uint_as_float(((unsigned int)h) << 16);
}
__device__ __forceinline__ unsigned int pk2bf(float a, float b) {
#if __has_builtin(__builtin_amdgcn_cvt_pk_bf16_f32)
    bf16x2 v = __builtin_amdgcn_cvt_pk_bf16_f32(a, b);
    return __builtin_bit_cast(unsigned int, v);
#else
    return (unsigned int)f2bf(a) | ((unsigned int)f2bf(b) << 16);
#endif
}
__device__ __forceinline__ float fexp2(float x) {
#if __has_builtin(__builtin_amdgcn_exp2f)
    return __builtin_amdgcn_exp2f(x);   // raw v_exp_f32; args bounded +-1.33
#else
    return exp2f(x);
#endif
}

// async global->LDS, 16B per lane; LDS dest = wave-uniform base + lane*16
__device__ __forceinline__ void gl_lds16(const void* g, void* l) {
    typedef __attribute__((address_space(1))) unsigned int GU;
    typedef __attribute__((address_space(3))) unsigned int LU;
    __builtin_amdgcn_global_load_lds((GU*)(unsigned long long)g,
                                     (LU*)(unsigned int)(unsigned long long)l,
                                     16, 0, 0);
}

__device__ __forceinline__ void wait_vm0() {
    asm volatile("s_waitcnt vmcnt(0)" ::: "memory");
}

// ---------------- K0: fused fp32 -> bf16 convert (x, w_qkv, w_o) ----------
__global__ void cvt3_kernel(const float* __restrict__ x,
                            const float* __restrict__ wqkv,
                            const float* __restrict__ wo,
                            unsigned short* __restrict__ xb,
                            unsigned short* __restrict__ wqkvb,
                            unsigned short* __restrict__ wob) {
    int i = blockIdx.x * 256 + threadIdx.x;
    const float* src;
    unsigned short* dst;
    int off;
    if (i < 1048576) { src = x; dst = xb; off = i; }
    else if (i < 1835008) { src = wqkv; dst = wqkvb; off = i - 1048576; }
    else { src = wo; dst = wob; off = i - 1835008; }
    float4 f = ((const float4*)src)[off];
    u16x4 o;
    o[0] = f2bf(f.x); o[1] = f2bf(f.y); o[2] = f2bf(f.z); o[3] = f2bf(f.w);
    ((u16x4*)dst)[off] = o;
}

// ---------------- K1: qkv GEMM + fused rmsnorm/rope/pack epilogue ----------
// R3 config: 128x128xBK64 single-buffer (m97 structure), 3/CU, XOR swizzle.
#define TBS 72
__global__ __launch_bounds__(256, 3) void gemm_qkv(
    const unsigned short* __restrict__ A,    // xb [4096][1024]
    const unsigned short* __restrict__ Bt,   // wqkvb [3072][1024]
    const float* __restrict__ cosb, const float* __restrict__ sinb,  // [T][16]
    const float* __restrict__ qw, const float* __restrict__ kw,      // [64]
    unsigned short* __restrict__ Qb,  // [H][T][64] (pre-scaled)
    unsigned short* __restrict__ Kb,  // [H][T][64]
    unsigned short* __restrict__ Vt)  // [H][64][T] (pre-scaled by 0.5)
{
    __shared__ unsigned short smem[16384];  // 32 KB
    unsigned short* As0 = smem;             // [128][32]
    unsigned short* As1 = smem + 4096;
    unsigned short* Bs0 = smem + 8192;
    unsigned short* Bs1 = smem + 12288;

    const int tid = threadIdx.x;
    const int wave = tid >> 6, lane = tid & 63;
    const int quad = lane >> 4, l16 = lane & 15;
    const int m0 = blockIdx.x * 128, n0 = blockIdx.y * 128;
    const int wm = (wave >> 1) * 64, wn = (wave & 1) * 64;

    f32x4 acc[4][4];
#pragma unroll
    for (int i = 0; i < 4; ++i)
#pragma unroll
        for (int j = 0; j < 4; ++j) acc[i][j] = (f32x4){0.f, 0.f, 0.f, 0.f};

    const int lrow = lane >> 2;
    const int lcol = ((lane & 3) ^ ((lane >> 3) & 3)) * 8;   // swizzled src chunk
    const int csw  = (quad ^ ((l16 >> 1) & 3)) * 8;          // swizzled read chunk

    for (int k0 = 0; k0 < 1024; k0 += 64) {
        {
            const unsigned short* ab = A + (size_t)(m0 + wave * 16 + lrow) * 1024 + k0 + lcol;
            gl_lds16(ab,              &As0[wave * 512]);
            gl_lds16(ab + 32,         &As1[wave * 512]);
            gl_lds16(ab + 65536,      &As0[2048 + wave * 512]);   // rows +64
            gl_lds16(ab + 65536 + 32, &As1[2048 + wave * 512]);
            const unsigned short* bb = Bt + (size_t)(n0 + wave * 16 + lrow) * 1024 + k0 + lcol;
            gl_lds16(bb,              &Bs0[wave * 512]);
            gl_lds16(bb + 32,         &Bs1[wave * 512]);
            gl_lds16(bb + 65536,      &Bs0[2048 + wave * 512]);
            gl_lds16(bb + 65536 + 32, &Bs1[2048 + wave * 512]);
        }
        __syncthreads();
        {
            bf16x8 af[4], bfr[4];
#pragma unroll
            for (int mt = 0; mt < 4; ++mt)
                af[mt] = *(const bf16x8*)&As0[(wm + mt * 16 + l16) * 32 + csw];
#pragma unroll
            for (int nt = 0; nt < 4; ++nt)
                bfr[nt] = *(const bf16x8*)&Bs0[(wn + nt * 16 + l16) * 32 + csw];
#pragma unroll
            for (int mt = 0; mt < 4; ++mt)
#pragma unroll
                for (int nt = 0; nt < 4; ++nt)
                    acc[mt][nt] = MFMA16(af[mt], bfr[nt], acc[mt][nt]);
        }
        {
            bf16x8 af[4], bfr[4];
#pragma unroll
            for (int mt = 0; mt < 4; ++mt)
                af[mt] = *(const bf16x8*)&As1[(wm + mt * 16 + l16) * 32 + csw];
#pragma unroll
            for (int nt = 0; nt < 4; ++nt)
                bfr[nt] = *(const bf16x8*)&Bs1[(wn + nt * 16 + l16) * 32 + csw];
#pragma unroll
            for (int mt = 0; mt < 4; ++mt)
#pragma unroll
                for (int nt = 0; nt < 4; ++nt)
                    acc[mt][nt] = MFMA16(af[mt], bfr[nt], acc[mt][nt]);
        }
        __syncthreads();
    }

    unsigned short* tbw = smem + wave * 1152;
    const int region = blockIdx.y >> 3;
    const int h = ((blockIdx.y & 7) << 1) + (wave & 1);

    if (region < 2) {
        const float* wgt = region ? kw : qw;
        unsigned short* dst = region ? Kb : Qb;
        const float post = region ? 1.f : 0.17312340490667046f;
        float w[4];
#pragma unroll
        for (int nt = 0; nt < 4; ++nt) w[nt] = wgt[nt * 16 + l16] * post;
#pragma unroll
        for (int mt = 0; mt < 4; ++mt) {
#pragma unroll
            for (int r = 0; r < 4; ++r) {
                const int row = m0 + wm + mt * 16 + quad * 4 + r;
                float ss = 0.f;
#pragma unroll
                for (int nt = 0; nt < 4; ++nt)
                    ss += acc[mt][nt][r] * acc[mt][nt][r];
                ss += __shfl_xor(ss, 1); ss += __shfl_xor(ss, 2);
                ss += __shfl_xor(ss, 4); ss += __shfl_xor(ss, 8);
                const float rn = rsqrtf(ss * (1.f / 64.f) + 1e-6f);
                float val[4];
#pragma unroll
                for (int nt = 0; nt < 4; ++nt)
                    val[nt] = acc[mt][nt][r] * rn * w[nt];
#pragma unroll
                for (int nt = 0; nt < 2; ++nt) {
                    const float prt = __shfl_xor(val[nt], 1);
                    const int p = nt * 8 + (l16 >> 1);
                    const float c = cosb[row * 16 + p];
                    const float s = sinb[row * 16 + p];
                    val[nt] = (l16 & 1) ? (prt * s + val[nt] * c)
                                        : (val[nt] * c - prt * s);
                }
#pragma unroll
                for (int nt = 0; nt < 4; ++nt)
                    tbw[(quad * 4 + r) * TBS + nt * 16 + l16] = f2bf(val[nt]);
            }
            const int t = lane >> 2, dcol = (lane & 3) * 16;
            u16x8 v0 = *(const u16x8*)&tbw[t * TBS + dcol];
            u16x8 v1 = *(const u16x8*)&tbw[t * TBS + dcol + 8];
            const size_t ob = ((size_t)h * 4096 + (m0 + wm + mt * 16 + t)) * 64 + dcol;
            *(u16x8*)&dst[ob] = v0;
            *(u16x8*)&dst[ob + 8] = v1;
        }
    } else {
#pragma unroll
        for (int mt = 0; mt < 4; ++mt) {
#pragma unroll
            for (int nt = 0; nt < 4; ++nt)
#pragma unroll
                for (int r = 0; r < 4; ++r)
                    tbw[(nt * 16 + l16) * 16 + quad * 4 + r] =
                        f2bf(acc[mt][nt][r] * 0.5f);
            u16x8 v0 = *(const u16x8*)&tbw[lane * 16];
            u16x8 v1 = *(const u16x8*)&tbw[lane * 16 + 8];
            const size_t vo = ((size_t)h * 64 + lane) * 4096 + m0 + wm + mt * 16;
            *(u16x8*)&Vt[vo] = v0;
            *(u16x8*)&Vt[vo + 8] = v1;
        }
    }
}

// ---------------- K2: sliding-window flash attention ----------------------
// R5: raw s_barrier + role-split counted vmcnt (K-wave drain at barrier2,
// V-wave drain at barrier1). 128-key tiles, K dbuf + early-V, per-half
// dead/clean skip, setprio around PV. 8 waves/128q. LDS 66KB, 2 blocks/CU.
#define PSTR 72  // P row stride (>=64 required; 144 B, 16B-aligned)

template <int MASK>
__device__ __forceinline__ void qk_exp(
    int sb, int tq, int quad, int l16, int csw, int rbase,
    const unsigned short* KsA, const unsigned short* KsB,
    unsigned short* Pw, const bf16x8 qf0, const bf16x8 qf1, float& lsum)
{
#pragma unroll
    for (int i = 0; i < 4; ++i) {
        // Z_i = K_i * Q^T: A-frag = K rows (contiguous d); C: row=key col=query
        const bf16x8 kf0 = *(const bf16x8*)&KsA[(rbase + i * 16 + l16) * 32 + csw];
        const bf16x8 kf1 = *(const bf16x8*)&KsB[(rbase + i * 16 + l16) * 32 + csw];
        f32x4 z = (f32x4){0.f, 0.f, 0.f, 0.f};
        z = MFMA16(kf0, qf0, z);
        z = MFMA16(kf1, qf1, z);
        float p[4];
#pragma unroll
        for (int r = 0; r < 4; ++r) {
            float e = fexp2(z[r]);   // scale pre-folded into Q
            if (MASK) {              // causal + window in one unsigned compare
                const int s = sb + i * 16 + quad * 4 + r;
                e = ((unsigned)(tq - s) < 1024u) ? e : 0.f;
            }
            p[r] = e;
            lsum += e;
        }
        uint2 pk;
        pk.x = pk2bf(p[0], p[1]);
        pk.y = pk2bf(p[2], p[3]);
        *(uint2*)&Pw[l16 * PSTR + i * 16 + quad * 4] = pk;
    }
}

__device__ __forceinline__ void pv_acc(
    int quad, int l16, int csw,
    const unsigned short* VsA, const unsigned short* VsB,
    const unsigned short* Pw, f32x4 (&o)[4])
{
    // P read (A-operand) — wave-private, in-order LDS + lgkmcnt suffices
    const bf16x8 pf0 = *(const bf16x8*)&Pw[l16 * PSTR + quad * 8];
    const bf16x8 pf1 = *(const bf16x8*)&Pw[l16 * PSTR + 32 + quad * 8];
    __builtin_amdgcn_s_setprio(1);
#pragma unroll
    for (int dt = 0; dt < 4; ++dt) {
        const bf16x8 vf0 = *(const bf16x8*)&VsA[(dt * 16 + l16) * 32 + csw];
        const bf16x8 vf1 = *(const bf16x8*)&VsB[(dt * 16 + l16) * 32 + csw];
        o[dt] = MFMA16(pf0, vf0, o[dt]);
        o[dt] = MFMA16(pf1, vf1, o[dt]);
    }
    __builtin_amdgcn_s_setprio(0);
}

__global__ __launch_bounds__(512, 4) void attn_kernel(
    const unsigned short* __restrict__ Qb,  // [H][T][64] (pre-scaled)
    const unsigned short* __restrict__ Kb,  // [H][T][64]
    const unsigned short* __restrict__ Vt,  // [H][64][T] (pre-scaled by 0.5)
    unsigned short* __restrict__ att)       // [T][1024]
{
    __shared__ unsigned short KsA[2][4096], KsB[2][4096];   // [128 keys][32 d]
    __shared__ unsigned short Vs0[2048], Vs1[2048];         // [64 d][32 t] (t 0-63)
    __shared__ unsigned short Vs2[2048], Vs3[2048];         // (t 64-127)
    __shared__ unsigned short P[8][16 * PSTR];

    // swizzle: h-pair = bid&7 (XCD locality); t descending (LPT balance)
    const int bid = blockIdx.x;
    const int h = ((bid & 7) << 1) | ((bid >> 3) & 1);
    const int t0 = (31 - (bid >> 4)) * 128;

    const int tid = threadIdx.x;
    const int wave = tid >> 6, lane = tid & 63;
    const int quad = lane >> 4, l16 = lane & 15;
    const int qt0 = t0 + wave * 16;
    const int tq = qt0 + l16;        // this lane's query (S^T col)
    // staging: waves 0-3 stage K (4 gl_lds), waves 4-7 stage V (4 gl_lds)
    const int srow = (tid & 255) >> 2;
    const int scol = ((tid & 3) ^ ((tid >> 3) & 3)) * 8;   // swizzled src chunk
    const int csw  = (quad ^ ((l16 >> 1) & 3)) * 8;        // swizzled read chunk

    const unsigned short* Qh = Qb + (size_t)h * 4096 * 64;
    const unsigned short* Kh = Kb + (size_t)h * 4096 * 64;
    const unsigned short* Vh = Vt + (size_t)h * 64 * 4096;

    const bf16x8 qf0 = *(const bf16x8*)&Qh[(qt0 + l16) * 64 + quad * 8];
    const bf16x8 qf1 = *(const bf16x8*)&Qh[(qt0 + l16) * 64 + 32 + quad * 8];

    f32x4 o[4];
#pragma unroll
    for (int dt = 0; dt < 4; ++dt) o[dt] = (f32x4){0.f, 0.f, 0.f, 0.f};
    float lsum = 0.f;
    unsigned short* Pw = P[wave];

    auto stageK = [&](int b, int s) {
        if (wave < 4) {
            const unsigned short* kb = Kh + (size_t)(s + srow) * 64 + scol;
            gl_lds16(kb,             &KsA[b][wave * 512]);
            gl_lds16(kb + 32,        &KsB[b][wave * 512]);
            gl_lds16(kb + 4096,      &KsA[b][2048 + wave * 512]);  // rows +64
            gl_lds16(kb + 4096 + 32, &KsB[b][2048 + wave * 512]);
        }
    };
    auto stageV = [&](int s) {
        if (wave >= 4) {
            const unsigned short* vb = Vh + (size_t)srow * 4096 + s + scol;
            gl_lds16(vb,      &Vs0[(wave - 4) * 512]);
            gl_lds16(vb + 32, &Vs1[(wave - 4) * 512]);
            gl_lds16(vb + 64, &Vs2[(wave - 4) * 512]);
            gl_lds16(vb + 96, &Vs3[(wave - 4) * 512]);
        }
    };

    const int s_lo = (t0 >= 1024) ? (t0 - 1024) : 0;
    const int NT = ((t0 - s_lo) >> 7) + 1;   // 128-key tiles

    stageK(0, s_lo);
    if (wave < 4) wait_vm0();      // only K-staging waves have loads in flight
    __builtin_amdgcn_s_barrier();  // publish K(0)
    __builtin_amdgcn_sched_barrier(0);
    int buf = 0;
    for (int n = 0; n < NT; ++n) {
        const int s0 = s_lo + n * 128;
        const int sb1 = s0 + 64;
        if (n + 1 < NT) stageK(buf ^ 1, s0 + 128);   // in flight across barrier1
        stageV(s0);                                  // drained at barrier1
        // per-half, per-wave classification (wave-uniform branches)
        const bool d0 = (s0 + 63 < qt0 - 1023);      // h0 never future-dead
        const bool c0 = (s0 + 63 <= qt0) && (s0 >= qt0 - 1008);
        const bool d1 = (sb1 > qt0 + 15) || (sb1 + 63 < qt0 - 1023);
        const bool c1 = (sb1 + 63 <= qt0) && (sb1 >= qt0 - 1008);
        if (!d0) {
            if (c0) qk_exp<0>(s0, tq, quad, l16, csw, 0, KsA[buf], KsB[buf],
                              Pw, qf0, qf1, lsum);
            else    qk_exp<1>(s0, tq, quad, l16, csw, 0, KsA[buf], KsB[buf],
                              Pw, qf0, qf1, lsum);
        }
        if (wave >= 4) wait_vm0();     // V(n) done; K(n+1) stays in flight
        __builtin_amdgcn_s_barrier();  // publish V(n)
        __builtin_amdgcn_sched_barrier(0);
        if (!d0) pv_acc(quad, l16, csw, Vs0, Vs1, Pw, o);
        if (!d1) {
            if (c1) qk_exp<0>(sb1, tq, quad, l16, csw, 64, KsA[buf], KsB[buf],
                              Pw, qf0, qf1, lsum);
            else    qk_exp<1>(sb1, tq, quad, l16, csw, 64, KsA[buf], KsB[buf],
                              Pw, qf0, qf1, lsum);
            pv_acc(quad, l16, csw, Vs2, Vs3, Pw, o);
        }
        if (wave < 4) wait_vm0();      // K(n+1) done (covered by full tile)
        __builtin_amdgcn_s_barrier();  // publish K(n+1); protect Vs/Ks reuse
        __builtin_amdgcn_sched_barrier(0);
        buf ^= 1;
    }

    lsum += __shfl_xor(lsum, 16);
    lsum += __shfl_xor(lsum, 32);
    float lr[4];
#pragma unroll
    for (int r = 0; r < 4; ++r) lr[r] = 1.f / __shfl(lsum, quad * 4 + r);
#pragma unroll
    for (int dt = 0; dt < 4; ++dt)
#pragma unroll
        for (int r = 0; r < 4; ++r)
            att[(size_t)(qt0 + quad * 4 + r) * 1024 + h * 64 + dt * 16 + l16] =
                f2bf(o[dt][r] * lr[r]);
}

// ---------------- K3: output GEMM (BM=64, BN=128, BK=64, prefetch-dbuf) ---
// Session-measured-best config (512 blocks, 2/CU supply-starved regime:
// dbuf is the measured win there). + R2 XOR bank-swizzle.
__global__ __launch_bounds__(256) void gemm_out(
    const unsigned short* __restrict__ A,    // attb [4096][1024]
    const unsigned short* __restrict__ Bt,   // wob  [1024][1024]
    float* __restrict__ C)                   // [4096][1024]
{
    __shared__ unsigned short As0[2][2048], As1[2][2048];
    __shared__ unsigned short Bs0[2][4096], Bs1[2][4096];
    const int tid = threadIdx.x;
    const int wave = tid >> 6, lane = tid & 63;
    const int quad = lane >> 4, l16 = lane & 15;
    const int m0 = blockIdx.x * 64, n0 = blockIdx.y * 128;
    const int wm = (wave >> 1) * 32, wn = (wave & 1) * 64;
    const int lrow = lane >> 2;
    const int lcol = ((lane & 3) ^ ((lane >> 3) & 3)) * 8;   // swizzled src chunk
    const int csw  = (quad ^ ((l16 >> 1) & 3)) * 8;          // swizzled read chunk

    f32x4 acc[2][4];
#pragma unroll
    for (int i = 0; i < 2; ++i)
#pragma unroll
        for (int j = 0; j < 4; ++j) acc[i][j] = (f32x4){0.f, 0.f, 0.f, 0.f};

    auto stage = [&](int buf, int k0) {
        const unsigned short* ab = A + (size_t)(m0 + wave * 16 + lrow) * 1024 + k0 + lcol;
        gl_lds16(ab,      &As0[buf][wave * 512]);
        gl_lds16(ab + 32, &As1[buf][wave * 512]);
#pragma unroll
        for (int i = 0; i < 2; ++i) {
            const int c = wave * 2 + i;
            const unsigned short* bb = Bt + (size_t)(n0 + c * 16 + lrow) * 1024 + k0 + lcol;
            gl_lds16(bb,      &Bs0[buf][c * 512]);
            gl_lds16(bb + 32, &Bs1[buf][c * 512]);
        }
    };

    stage(0, 0);
    __syncthreads();
    int buf = 0;
    for (int k0 = 0; k0 < 1024; k0 += 64) {
        if (k0 + 64 < 1024) stage(buf ^ 1, k0 + 64);  // prefetch before compute
        {
            bf16x8 af[2], bfr[4];
#pragma unroll
            for (int mt = 0; mt < 2; ++mt)
                af[mt] = *(const bf16x8*)&As0[buf][(wm + mt * 16 + l16) * 32 + csw];
#pragma unroll
            for (int nt = 0; nt < 4; ++nt)
                bfr[nt] = *(const bf16x8*)&Bs0[buf][(wn + nt * 16 + l16) * 32 + csw];
#pragma unroll
            for (int mt = 0; mt < 2; ++mt)
#pragma unroll
                for (int nt = 0; nt < 4; ++nt)
                    acc[mt][nt] = MFMA16(af[mt], bfr[nt], acc[mt][nt]);
        }
        {
            bf16x8 af[2], bfr[4];
#pragma unroll
            for (int mt = 0; mt < 2; ++mt)
                af[mt] = *(const bf16x8*)&As1[buf][(wm + mt * 16 + l16) * 32 + csw];
#pragma unroll
            for (int nt = 0; nt < 4; ++nt)
                bfr[nt] = *(const bf16x8*)&Bs1[buf][(wn + nt * 16 + l16) * 32 + csw];
#pragma unroll
            for (int mt = 0; mt < 2; ++mt)
#pragma unroll
                for (int nt = 0; nt < 4; ++nt)
                    acc[mt][nt] = MFMA16(af[mt], bfr[nt], acc[mt][nt]);
        }
        __syncthreads();  // publishes prefetched tiles; protects buf reuse
        buf ^= 1;
    }
#pragma unroll
    for (int mt = 0; mt < 2; ++mt)
#pragma unroll
        for (int nt = 0; nt < 4; ++nt)
#pragma unroll
            for (int r = 0; r < 4; ++r) {
                const int row = m0 + wm + mt * 16 + quad * 4 + r;
                const int col = n0 + wn + nt * 16 + l16;
                C[(size_t)row * 1024 + col] = acc[mt][nt][r];
            }
}

// ---------------- launcher ----------------
extern "C" void kernel_launch(void* const* d_in, const int* in_sizes, int n_in,
                              void* d_out, int out_size, void* d_ws, size_t ws_size,
                              hipStream_t stream) {
    const float* x    = (const float*)d_in[0];
    const float* wqkv = (const float*)d_in[3];
    const float* wo   = (const float*)d_in[4];
    const float* qw   = (const float*)d_in[5];
    const float* kw   = (const float*)d_in[6];
    const float* cosb = (const float*)d_in[7];
    const float* sinb = (const float*)d_in[8];

    char* ws = (char*)d_ws;
    // ws (MiB): xb 0-8 | wqkvb 8-14 | wob 14-16 | Qb 16-24 | Kb 24-32
    //           Vt 32-40 | attb 40-48
    if (ws_size < (size_t)48 * 1024 * 1024) return;
    unsigned short* xb    = (unsigned short*)(ws + ((size_t)0 << 20));
    unsigned short* wqkvb = (unsigned short*)(ws + ((size_t)8 << 20));
    unsigned short* wob   = (unsigned short*)(ws + ((size_t)14 << 20));
    unsigned short* Qb    = (unsigned short*)(ws + ((size_t)16 << 20));
    unsigned short* Kb    = (unsigned short*)(ws + ((size_t)24 << 20));
    unsigned short* Vt    = (unsigned short*)(ws + ((size_t)32 << 20));
    unsigned short* attb  = (unsigned short*)(ws + ((size_t)40 << 20));

    // K0: fused converts (one launch)
    cvt3_kernel<<<8192, 256, 0, stream>>>(x, wqkv, wo, xb, wqkvb, wob);

    // K1: qkv GEMM + fused rmsnorm/rope/pack epilogue (128x128x64, 3/CU)
    gemm_qkv<<<dim3(32, 24), 256, 0, stream>>>(xb, wqkvb, cosb, sinb, qw, kw,
                                               Qb, Kb, Vt);

    // K2: sliding-window attention (role-split counted vmcnt + raw barriers)
    attn_kernel<<<512, 512, 0, stream>>>(Qb, Kb, Vt, attb);

    // K3: y = att @ w_o^T  (M=4096, N=1024, K=1024), fp32 out, BK64 dbuf
    gemm_out<<<dim3(64, 8), 256, 0, stream>>>(attb, wob, (float*)d_out);
}

// Round 6
// 173.269 us; speedup vs baseline: 1.0263x; 1.0263x over previous
//
#include <hip/hip_runtime.h>

// Problem constants (hardcoded from reference):
//   T=4096, D_MODEL=1024, N_HEADS=16, HEAD_DIM=64, ROT=32, PAIR=16,
//   EPS=1e-6, SCALE=0.12, WINDOW=1024. tokens/pos/block_size unused.
//
// Attention numerics: rmsnorm => ||q||=||k||=8, so |q.k|*SCALE <= 7.68 ->
// exp bounded [4.6e-4, 2164]: softmax max-subtraction unnecessary.
// SCALE*log2(e) pre-folded into Q at the gemm_qkv epilogue: p = exp2(z).
//
// R6 changes (attn only; clean attribution):
//  - THEORY: attn is LDS-pipe-throughput-bound (~24 DS ops/wave/64-key half
//    at ~10-12cy each ~= 27us across the grid; explains R3/R4/R5 neutrality
//    of all scheduling changes and MfmaUtil 13%/VALUBusy 35%/nothing-
//    saturated). K/V fragment LDS reads are independent of queries-per-wave
//    -> 32 q/wave (4 waves x 32q = same 128q/block, same tiles/barriers as
//    R5) cuts DS ops per query 36% and doubles MFMA per DS read.
//  - Staging re-split: waves 0-1 stage K (8 gl_lds each), waves 2-3 stage V
//    (8 each); identical per-load addressing shapes; role-split vmcnt kept.
//  - Occupancy 16 -> 8 waves/CU (accepted per theory; latency theory is
//    triple-falsified by R3/R4/R5).

typedef __bf16 bf16x8 __attribute__((ext_vector_type(8)));
typedef __bf16 bf16x2 __attribute__((ext_vector_type(2)));
typedef float f32x4 __attribute__((ext_vector_type(4)));
typedef unsigned short u16x8 __attribute__((ext_vector_type(8)));
typedef unsigned short u16x4 __attribute__((ext_vector_type(4)));

#define MFMA16(a, b, c) __builtin_amdgcn_mfma_f32_16x16x32_bf16((a), (b), (c), 0, 0, 0)

__device__ __forceinline__ unsigned short f2bf(float f) {
    unsigned int u = __float_as_uint(f);
    u += 0x7fffu + ((u >> 16) & 1u);   // round-to-nearest-even
    return (unsigned short)(u >> 16);
}
__device__ __forceinline__ float bf2f(unsigned short h) {
    return __uint_as_float(((unsigned int)h) << 16);
}
__device__ __forceinline__ unsigned int pk2bf(float a, float b) {
#if __has_builtin(__builtin_amdgcn_cvt_pk_bf16_f32)
    bf16x2 v = __builtin_amdgcn_cvt_pk_bf16_f32(a, b);
    return __builtin_bit_cast(unsigned int, v);
#else
    return (unsigned int)f2bf(a) | ((unsigned int)f2bf(b) << 16);
#endif
}
__device__ __forceinline__ float fexp2(float x) {
#if __has_builtin(__builtin_amdgcn_exp2f)
    return __builtin_amdgcn_exp2f(x);   // raw v_exp_f32; args bounded +-1.33
#else
    return exp2f(x);
#endif
}

// async global->LDS, 16B per lane; LDS dest = wave-uniform base + lane*16
__device__ __forceinline__ void gl_lds16(const void* g, void* l) {
    typedef __attribute__((address_space(1))) unsigned int GU;
    typedef __attribute__((address_space(3))) unsigned int LU;
    __builtin_amdgcn_global_load_lds((GU*)(unsigned long long)g,
                                     (LU*)(unsigned int)(unsigned long long)l,
                                     16, 0, 0);
}

__device__ __forceinline__ void wait_vm0() {
    asm volatile("s_waitcnt vmcnt(0)" ::: "memory");
}

// ---------------- K0: fused fp32 -> bf16 convert (x, w_qkv, w_o) ----------
__global__ void cvt3_kernel(const float* __restrict__ x,
                            const float* __restrict__ wqkv,
                            const float* __restrict__ wo,
                            unsigned short* __restrict__ xb,
                            unsigned short* __restrict__ wqkvb,
                            unsigned short* __restrict__ wob) {
    int i = blockIdx.x * 256 + threadIdx.x;
    const float* src;
    unsigned short* dst;
    int off;
    if (i < 1048576) { src = x; dst = xb; off = i; }
    else if (i < 1835008) { src = wqkv; dst = wqkvb; off = i - 1048576; }
    else { src = wo; dst = wob; off = i - 1835008; }
    float4 f = ((const float4*)src)[off];
    u16x4 o;
    o[0] = f2bf(f.x); o[1] = f2bf(f.y); o[2] = f2bf(f.z); o[3] = f2bf(f.w);
    ((u16x4*)dst)[off] = o;
}

// ---------------- K1: qkv GEMM + fused rmsnorm/rope/pack epilogue ----------
// R3 config: 128x128xBK64 single-buffer (m97 structure), 3/CU, XOR swizzle.
#define TBS 72
__global__ __launch_bounds__(256, 3) void gemm_qkv(
    const unsigned short* __restrict__ A,    // xb [4096][1024]
    const unsigned short* __restrict__ Bt,   // wqkvb [3072][1024]
    const float* __restrict__ cosb, const float* __restrict__ sinb,  // [T][16]
    const float* __restrict__ qw, const float* __restrict__ kw,      // [64]
    unsigned short* __restrict__ Qb,  // [H][T][64] (pre-scaled)
    unsigned short* __restrict__ Kb,  // [H][T][64]
    unsigned short* __restrict__ Vt)  // [H][64][T] (pre-scaled by 0.5)
{
    __shared__ unsigned short smem[16384];  // 32 KB
    unsigned short* As0 = smem;             // [128][32]
    unsigned short* As1 = smem + 4096;
    unsigned short* Bs0 = smem + 8192;
    unsigned short* Bs1 = smem + 12288;

    const int tid = threadIdx.x;
    const int wave = tid >> 6, lane = tid & 63;
    const int quad = lane >> 4, l16 = lane & 15;
    const int m0 = blockIdx.x * 128, n0 = blockIdx.y * 128;
    const int wm = (wave >> 1) * 64, wn = (wave & 1) * 64;

    f32x4 acc[4][4];
#pragma unroll
    for (int i = 0; i < 4; ++i)
#pragma unroll
        for (int j = 0; j < 4; ++j) acc[i][j] = (f32x4){0.f, 0.f, 0.f, 0.f};

    const int lrow = lane >> 2;
    const int lcol = ((lane & 3) ^ ((lane >> 3) & 3)) * 8;   // swizzled src chunk
    const int csw  = (quad ^ ((l16 >> 1) & 3)) * 8;          // swizzled read chunk

    for (int k0 = 0; k0 < 1024; k0 += 64) {
        {
            const unsigned short* ab = A + (size_t)(m0 + wave * 16 + lrow) * 1024 + k0 + lcol;
            gl_lds16(ab,              &As0[wave * 512]);
            gl_lds16(ab + 32,         &As1[wave * 512]);
            gl_lds16(ab + 65536,      &As0[2048 + wave * 512]);   // rows +64
            gl_lds16(ab + 65536 + 32, &As1[2048 + wave * 512]);
            const unsigned short* bb = Bt + (size_t)(n0 + wave * 16 + lrow) * 1024 + k0 + lcol;
            gl_lds16(bb,              &Bs0[wave * 512]);
            gl_lds16(bb + 32,         &Bs1[wave * 512]);
            gl_lds16(bb + 65536,      &Bs0[2048 + wave * 512]);
            gl_lds16(bb + 65536 + 32, &Bs1[2048 + wave * 512]);
        }
        __syncthreads();
        {
            bf16x8 af[4], bfr[4];
#pragma unroll
            for (int mt = 0; mt < 4; ++mt)
                af[mt] = *(const bf16x8*)&As0[(wm + mt * 16 + l16) * 32 + csw];
#pragma unroll
            for (int nt = 0; nt < 4; ++nt)
                bfr[nt] = *(const bf16x8*)&Bs0[(wn + nt * 16 + l16) * 32 + csw];
#pragma unroll
            for (int mt = 0; mt < 4; ++mt)
#pragma unroll
                for (int nt = 0; nt < 4; ++nt)
                    acc[mt][nt] = MFMA16(af[mt], bfr[nt], acc[mt][nt]);
        }
        {
            bf16x8 af[4], bfr[4];
#pragma unroll
            for (int mt = 0; mt < 4; ++mt)
                af[mt] = *(const bf16x8*)&As1[(wm + mt * 16 + l16) * 32 + csw];
#pragma unroll
            for (int nt = 0; nt < 4; ++nt)
                bfr[nt] = *(const bf16x8*)&Bs1[(wn + nt * 16 + l16) * 32 + csw];
#pragma unroll
            for (int mt = 0; mt < 4; ++mt)
#pragma unroll
                for (int nt = 0; nt < 4; ++nt)
                    acc[mt][nt] = MFMA16(af[mt], bfr[nt], acc[mt][nt]);
        }
        __syncthreads();
    }

    unsigned short* tbw = smem + wave * 1152;
    const int region = blockIdx.y >> 3;
    const int h = ((blockIdx.y & 7) << 1) + (wave & 1);

    if (region < 2) {
        const float* wgt = region ? kw : qw;
        unsigned short* dst = region ? Kb : Qb;
        const float post = region ? 1.f : 0.17312340490667046f;
        float w[4];
#pragma unroll
        for (int nt = 0; nt < 4; ++nt) w[nt] = wgt[nt * 16 + l16] * post;
#pragma unroll
        for (int mt = 0; mt < 4; ++mt) {
#pragma unroll
            for (int r = 0; r < 4; ++r) {
                const int row = m0 + wm + mt * 16 + quad * 4 + r;
                float ss = 0.f;
#pragma unroll
                for (int nt = 0; nt < 4; ++nt)
                    ss += acc[mt][nt][r] * acc[mt][nt][r];
                ss += __shfl_xor(ss, 1); ss += __shfl_xor(ss, 2);
                ss += __shfl_xor(ss, 4); ss += __shfl_xor(ss, 8);
                const float rn = rsqrtf(ss * (1.f / 64.f) + 1e-6f);
                float val[4];
#pragma unroll
                for (int nt = 0; nt < 4; ++nt)
                    val[nt] = acc[mt][nt][r] * rn * w[nt];
#pragma unroll
                for (int nt = 0; nt < 2; ++nt) {
                    const float prt = __shfl_xor(val[nt], 1);
                    const int p = nt * 8 + (l16 >> 1);
                    const float c = cosb[row * 16 + p];
                    const float s = sinb[row * 16 + p];
                    val[nt] = (l16 & 1) ? (prt * s + val[nt] * c)
                                        : (val[nt] * c - prt * s);
                }
#pragma unroll
                for (int nt = 0; nt < 4; ++nt)
                    tbw[(quad * 4 + r) * TBS + nt * 16 + l16] = f2bf(val[nt]);
            }
            const int t = lane >> 2, dcol = (lane & 3) * 16;
            u16x8 v0 = *(const u16x8*)&tbw[t * TBS + dcol];
            u16x8 v1 = *(const u16x8*)&tbw[t * TBS + dcol + 8];
            const size_t ob = ((size_t)h * 4096 + (m0 + wm + mt * 16 + t)) * 64 + dcol;
            *(u16x8*)&dst[ob] = v0;
            *(u16x8*)&dst[ob + 8] = v1;
        }
    } else {
#pragma unroll
        for (int mt = 0; mt < 4; ++mt) {
#pragma unroll
            for (int nt = 0; nt < 4; ++nt)
#pragma unroll
                for (int r = 0; r < 4; ++r)
                    tbw[(nt * 16 + l16) * 16 + quad * 4 + r] =
                        f2bf(acc[mt][nt][r] * 0.5f);
            u16x8 v0 = *(const u16x8*)&tbw[lane * 16];
            u16x8 v1 = *(const u16x8*)&tbw[lane * 16 + 8];
            const size_t vo = ((size_t)h * 64 + lane) * 4096 + m0 + wm + mt * 16;
            *(u16x8*)&Vt[vo] = v0;
            *(u16x8*)&Vt[vo + 8] = v1;
        }
    }
}

// ---------------- K2: sliding-window flash attention ----------------------
// R6: 4 waves x 32 queries (128q/block, grid unchanged), 128-key tiles,
// K dbuf + early-V, role-split counted vmcnt + raw barriers, XOR swizzle,
// per-half dead/clean skip, setprio around PV. LDS 66KB -> 2 blocks/CU.
#define PSTR 72  // P row stride (>=64 required; 144 B, 16B-aligned)

template <int MASK>
__device__ __forceinline__ void qk_exp_2g(
    int sb, int qt0w, int quad, int l16, int csw, int rbase,
    const unsigned short* KsA, const unsigned short* KsB,
    unsigned short* Pw, const bf16x8 (&qf)[2][2], float (&lsum)[2])
{
#pragma unroll
    for (int i = 0; i < 4; ++i) {
        // K-frags read ONCE, feed both query groups (the R6 amortization)
        const bf16x8 kf0 = *(const bf16x8*)&KsA[(rbase + i * 16 + l16) * 32 + csw];
        const bf16x8 kf1 = *(const bf16x8*)&KsB[(rbase + i * 16 + l16) * 32 + csw];
#pragma unroll
        for (int g = 0; g < 2; ++g) {
            f32x4 z = (f32x4){0.f, 0.f, 0.f, 0.f};
            z = MFMA16(kf0, qf[g][0], z);
            z = MFMA16(kf1, qf[g][1], z);
            float p[4];
#pragma unroll
            for (int r = 0; r < 4; ++r) {
                float e = fexp2(z[r]);   // scale pre-folded into Q
                if (MASK) {              // causal + window in one unsigned compare
                    const int s = sb + i * 16 + quad * 4 + r;
                    e = ((unsigned)((qt0w + g * 16 + l16) - s) < 1024u) ? e : 0.f;
                }
                p[r] = e;
                lsum[g] += e;
            }
            uint2 pk;
            pk.x = pk2bf(p[0], p[1]);
            pk.y = pk2bf(p[2], p[3]);
            *(uint2*)&Pw[(g * 16 + l16) * PSTR + i * 16 + quad * 4] = pk;
        }
    }
}

__device__ __forceinline__ void pv_acc_2g(
    int quad, int l16, int csw,
    const unsigned short* VsA, const unsigned short* VsB,
    const unsigned short* Pw, f32x4 (&o)[2][4])
{
    // P read (A-operand) — wave-private, in-order LDS + lgkmcnt suffices
    bf16x8 pf0[2], pf1[2];
#pragma unroll
    for (int g = 0; g < 2; ++g) {
        pf0[g] = *(const bf16x8*)&Pw[(g * 16 + l16) * PSTR + quad * 8];
        pf1[g] = *(const bf16x8*)&Pw[(g * 16 + l16) * PSTR + 32 + quad * 8];
    }
    __builtin_amdgcn_s_setprio(1);
#pragma unroll
    for (int dt = 0; dt < 4; ++dt) {
        // V-frags read ONCE, feed both query groups
        const bf16x8 vf0 = *(const bf16x8*)&VsA[(dt * 16 + l16) * 32 + csw];
        const bf16x8 vf1 = *(const bf16x8*)&VsB[(dt * 16 + l16) * 32 + csw];
#pragma unroll
        for (int g = 0; g < 2; ++g) {
            o[g][dt] = MFMA16(pf0[g], vf0, o[g][dt]);
            o[g][dt] = MFMA16(pf1[g], vf1, o[g][dt]);
        }
    }
    __builtin_amdgcn_s_setprio(0);
}

__global__ __launch_bounds__(256) void attn_kernel(
    const unsigned short* __restrict__ Qb,  // [H][T][64] (pre-scaled)
    const unsigned short* __restrict__ Kb,  // [H][T][64]
    const unsigned short* __restrict__ Vt,  // [H][64][T] (pre-scaled by 0.5)
    unsigned short* __restrict__ att)       // [T][1024]
{
    __shared__ unsigned short KsA[2][4096], KsB[2][4096];   // [128 keys][32 d]
    __shared__ unsigned short Vs0[2048], Vs1[2048];         // [64 d][32 t] (t 0-63)
    __shared__ unsigned short Vs2[2048], Vs3[2048];         // (t 64-127)
    __shared__ unsigned short P[4][32 * PSTR];

    // swizzle: h-pair = bid&7 (XCD locality); t descending (LPT balance)
    const int bid = blockIdx.x;
    const int h = ((bid & 7) << 1) | ((bid >> 3) & 1);
    const int t0 = (31 - (bid >> 4)) * 128;

    const int tid = threadIdx.x;
    const int wave = tid >> 6, lane = tid & 63;
    const int quad = lane >> 4, l16 = lane & 15;
    const int qt0 = t0 + wave * 32;  // 32 queries per wave
    const int srow = lane >> 2;                              // 0..15
    const int scol = ((lane & 3) ^ ((lane >> 3) & 3)) * 8;   // swizzled src chunk
    const int csw  = (quad ^ ((l16 >> 1) & 3)) * 8;          // swizzled read chunk

    const unsigned short* Qh = Qb + (size_t)h * 4096 * 64;
    const unsigned short* Kh = Kb + (size_t)h * 4096 * 64;
    const unsigned short* Vh = Vt + (size_t)h * 64 * 4096;

    bf16x8 qf[2][2];
#pragma unroll
    for (int g = 0; g < 2; ++g) {
        qf[g][0] = *(const bf16x8*)&Qh[(qt0 + g * 16 + l16) * 64 + quad * 8];
        qf[g][1] = *(const bf16x8*)&Qh[(qt0 + g * 16 + l16) * 64 + 32 + quad * 8];
    }

    f32x4 o[2][4];
#pragma unroll
    for (int g = 0; g < 2; ++g)
#pragma unroll
        for (int dt = 0; dt < 4; ++dt) o[g][dt] = (f32x4){0.f, 0.f, 0.f, 0.f};
    float lsum[2] = {0.f, 0.f};
    unsigned short* Pw = P[wave];

    // staging: waves 0-1 stage K (8 gl_lds each), waves 2-3 stage V (8 each)
    auto stageK = [&](int b, int s) {
        if (wave < 2) {
#pragma unroll
            for (int l = 0; l < 4; ++l) {
                const int rg = wave * 4 + l;   // row-group 0..7 (16 rows each)
                const unsigned short* kb =
                    Kh + (size_t)(s + rg * 16 + srow) * 64 + scol;
                gl_lds16(kb,      &KsA[b][rg * 512]);
                gl_lds16(kb + 32, &KsB[b][rg * 512]);
            }
        }
    };
    auto stageV = [&](int s) {
        if (wave >= 2) {
            const int w2 = wave - 2;
#pragma unroll
            for (int l = 0; l < 2; ++l) {
                const int dg = w2 * 2 + l;     // d-group 0..3 (16 d-rows each)
                const unsigned short* vb =
                    Vh + (size_t)(dg * 16 + srow) * 4096 + s + scol;
                gl_lds16(vb,      &Vs0[dg * 512]);
                gl_lds16(vb + 32, &Vs1[dg * 512]);
                gl_lds16(vb + 64, &Vs2[dg * 512]);
                gl_lds16(vb + 96, &Vs3[dg * 512]);
            }
        }
    };

    const int s_lo = (t0 >= 1024) ? (t0 - 1024) : 0;
    const int NT = ((t0 - s_lo) >> 7) + 1;   // 128-key tiles

    stageK(0, s_lo);
    if (wave < 2) wait_vm0();      // only K-staging waves have loads in flight
    __builtin_amdgcn_s_barrier();  // publish K(0)
    __builtin_amdgcn_sched_barrier(0);
    int buf = 0;
    for (int n = 0; n < NT; ++n) {
        const int s0 = s_lo + n * 128;
        const int sb1 = s0 + 64;
        if (n + 1 < NT) stageK(buf ^ 1, s0 + 128);   // in flight across barrier1
        stageV(s0);                                  // drained at barrier1
        // per-half, per-wave classification (wave-uniform; 32q: qlo..qlo+31)
        const bool d0 = (s0 + 63 < qt0 - 1023);      // h0 never future-dead
        const bool c0 = (s0 + 63 <= qt0) && (s0 >= qt0 - 992);
        const bool d1 = (sb1 > qt0 + 31) || (sb1 + 63 < qt0 - 1023);
        const bool c1 = (sb1 + 63 <= qt0) && (sb1 >= qt0 - 992);
        if (!d0) {
            if (c0) qk_exp_2g<0>(s0, qt0, quad, l16, csw, 0, KsA[buf], KsB[buf],
                                 Pw, qf, lsum);
            else    qk_exp_2g<1>(s0, qt0, quad, l16, csw, 0, KsA[buf], KsB[buf],
                                 Pw, qf, lsum);
        }
        if (wave >= 2) wait_vm0();     // V(n) done; K(n+1) stays in flight
        __builtin_amdgcn_s_barrier();  // publish V(n)
        __builtin_amdgcn_sched_barrier(0);
        if (!d0) pv_acc_2g(quad, l16, csw, Vs0, Vs1, Pw, o);
        if (!d1) {
            if (c1) qk_exp_2g<0>(sb1, qt0, quad, l16, csw, 64, KsA[buf], KsB[buf],
                                 Pw, qf, lsum);
            else    qk_exp_2g<1>(sb1, qt0, quad, l16, csw, 64, KsA[buf], KsB[buf],
                                 Pw, qf, lsum);
            pv_acc_2g(quad, l16, csw, Vs2, Vs3, Pw, o);
        }
        if (wave < 2) wait_vm0();      // K(n+1) done (covered by full tile)
        __builtin_amdgcn_s_barrier();  // publish K(n+1); protect Vs/Ks reuse
        __builtin_amdgcn_sched_barrier(0);
        buf ^= 1;
    }

#pragma unroll
    for (int g = 0; g < 2; ++g) {
        float ls = lsum[g];
        ls += __shfl_xor(ls, 16);
        ls += __shfl_xor(ls, 32);
        float lr[4];
#pragma unroll
        for (int r = 0; r < 4; ++r) lr[r] = 1.f / __shfl(ls, quad * 4 + r);
#pragma unroll
        for (int dt = 0; dt < 4; ++dt)
#pragma unroll
            for (int r = 0; r < 4; ++r)
                att[(size_t)(qt0 + g * 16 + quad * 4 + r) * 1024 +
                    h * 64 + dt * 16 + l16] = f2bf(o[g][dt][r] * lr[r]);
    }
}

// ---------------- K3: output GEMM (BM=64, BN=128, BK=64, prefetch-dbuf) ---
// Session-measured-best config (512 blocks, 2/CU supply-starved regime:
// dbuf is the measured win there). + R2 XOR bank-swizzle.
__global__ __launch_bounds__(256) void gemm_out(
    const unsigned short* __restrict__ A,    // attb [4096][1024]
    const unsigned short* __restrict__ Bt,   // wob  [1024][1024]
    float* __restrict__ C)                   // [4096][1024]
{
    __shared__ unsigned short As0[2][2048], As1[2][2048];
    __shared__ unsigned short Bs0[2][4096], Bs1[2][4096];
    const int tid = threadIdx.x;
    const int wave = tid >> 6, lane = tid & 63;
    const int quad = lane >> 4, l16 = lane & 15;
    const int m0 = blockIdx.x * 64, n0 = blockIdx.y * 128;
    const int wm = (wave >> 1) * 32, wn = (wave & 1) * 64;
    const int lrow = lane >> 2;
    const int lcol = ((lane & 3) ^ ((lane >> 3) & 3)) * 8;   // swizzled src chunk
    const int csw  = (quad ^ ((l16 >> 1) & 3)) * 8;          // swizzled read chunk

    f32x4 acc[2][4];
#pragma unroll
    for (int i = 0; i < 2; ++i)
#pragma unroll
        for (int j = 0; j < 4; ++j) acc[i][j] = (f32x4){0.f, 0.f, 0.f, 0.f};

    auto stage = [&](int buf, int k0) {
        const unsigned short* ab = A + (size_t)(m0 + wave * 16 + lrow) * 1024 + k0 + lcol;
        gl_lds16(ab,      &As0[buf][wave * 512]);
        gl_lds16(ab + 32, &As1[buf][wave * 512]);
#pragma unroll
        for (int i = 0; i < 2; ++i) {
            const int c = wave * 2 + i;
            const unsigned short* bb = Bt + (size_t)(n0 + c * 16 + lrow) * 1024 + k0 + lcol;
            gl_lds16(bb,      &Bs0[buf][c * 512]);
            gl_lds16(bb + 32, &Bs1[buf][c * 512]);
        }
    };

    stage(0, 0);
    __syncthreads();
    int buf = 0;
    for (int k0 = 0; k0 < 1024; k0 += 64) {
        if (k0 + 64 < 1024) stage(buf ^ 1, k0 + 64);  // prefetch before compute
        {
            bf16x8 af[2], bfr[4];
#pragma unroll
            for (int mt = 0; mt < 2; ++mt)
                af[mt] = *(const bf16x8*)&As0[buf][(wm + mt * 16 + l16) * 32 + csw];
#pragma unroll
            for (int nt = 0; nt < 4; ++nt)
                bfr[nt] = *(const bf16x8*)&Bs0[buf][(wn + nt * 16 + l16) * 32 + csw];
#pragma unroll
            for (int mt = 0; mt < 2; ++mt)
#pragma unroll
                for (int nt = 0; nt < 4; ++nt)
                    acc[mt][nt] = MFMA16(af[mt], bfr[nt], acc[mt][nt]);
        }
        {
            bf16x8 af[2], bfr[4];
#pragma unroll
            for (int mt = 0; mt < 2; ++mt)
                af[mt] = *(const bf16x8*)&As1[buf][(wm + mt * 16 + l16) * 32 + csw];
#pragma unroll
            for (int nt = 0; nt < 4; ++nt)
                bfr[nt] = *(const bf16x8*)&Bs1[buf][(wn + nt * 16 + l16) * 32 + csw];
#pragma unroll
            for (int mt = 0; mt < 2; ++mt)
#pragma unroll
                for (int nt = 0; nt < 4; ++nt)
                    acc[mt][nt] = MFMA16(af[mt], bfr[nt], acc[mt][nt]);
        }
        __syncthreads();  // publishes prefetched tiles; protects buf reuse
        buf ^= 1;
    }
#pragma unroll
    for (int mt = 0; mt < 2; ++mt)
#pragma unroll
        for (int nt = 0; nt < 4; ++nt)
#pragma unroll
            for (int r = 0; r < 4; ++r) {
                const int row = m0 + wm + mt * 16 + quad * 4 + r;
                const int col = n0 + wn + nt * 16 + l16;
                C[(size_t)row * 1024 + col] = acc[mt][nt][r];
            }
}

// ---------------- launcher ----------------
extern "C" void kernel_launch(void* const* d_in, const int* in_sizes, int n_in,
                              void* d_out, int out_size, void* d_ws, size_t ws_size,
                              hipStream_t stream) {
    const float* x    = (const float*)d_in[0];
    const float* wqkv = (const float*)d_in[3];
    const float* wo   = (const float*)d_in[4];
    const float* qw   = (const float*)d_in[5];
    const float* kw   = (const float*)d_in[6];
    const float* cosb = (const float*)d_in[7];
    const float* sinb = (const float*)d_in[8];

    char* ws = (char*)d_ws;
    // ws (MiB): xb 0-8 | wqkvb 8-14 | wob 14-16 | Qb 16-24 | Kb 24-32
    //           Vt 32-40 | attb 40-48
    if (ws_size < (size_t)48 * 1024 * 1024) return;
    unsigned short* xb    = (unsigned short*)(ws + ((size_t)0 << 20));
    unsigned short* wqkvb = (unsigned short*)(ws + ((size_t)8 << 20));
    unsigned short* wob   = (unsigned short*)(ws + ((size_t)14 << 20));
    unsigned short* Qb    = (unsigned short*)(ws + ((size_t)16 << 20));
    unsigned short* Kb    = (unsigned short*)(ws + ((size_t)24 << 20));
    unsigned short* Vt    = (unsigned short*)(ws + ((size_t)32 << 20));
    unsigned short* attb  = (unsigned short*)(ws + ((size_t)40 << 20));

    // K0: fused converts (one launch)
    cvt3_kernel<<<8192, 256, 0, stream>>>(x, wqkv, wo, xb, wqkvb, wob);

    // K1: qkv GEMM + fused rmsnorm/rope/pack epilogue (128x128x64, 3/CU)
    gemm_qkv<<<dim3(32, 24), 256, 0, stream>>>(xb, wqkvb, cosb, sinb, qw, kw,
                                               Qb, Kb, Vt);

    // K2: sliding-window attention (4 waves x 32q; LDS-read amortization)
    attn_kernel<<<512, 256, 0, stream>>>(Qb, Kb, Vt, attb);

    // K3: y = att @ w_o^T  (M=4096, N=1024, K=1024), fp32 out, BK64 dbuf
    gemm_out<<<dim3(64, 8), 256, 0, stream>>>(attb, wob, (float*)d_out);
}

// Round 7
// 172.635 us; speedup vs baseline: 1.0301x; 1.0037x over previous
//
#include <hip/hip_runtime.h>

// Problem constants (hardcoded from reference):
//   T=4096, D_MODEL=1024, N_HEADS=16, HEAD_DIM=64, ROT=32, PAIR=16,
//   EPS=1e-6, SCALE=0.12, WINDOW=1024. tokens/pos/block_size unused.
//
// Attention numerics: rmsnorm => ||q||=||k||=8, so |q.k|*SCALE <= 7.68 ->
// exp bounded [4.6e-4, 2164]: softmax max-subtraction unnecessary.
// SCALE*log2(e) pre-folded into Q at the gemm_qkv epilogue: p = exp2(z).
//
// R7 changes (attn instruction-budget, continuing R6's confirmed lever):
//  - lsum via ones-MFMA: ls = MFMA(pf, ones, ls) row-sums P on the MFMA pipe
//    (idle at ~15%), removing 32 VALU adds/half + the 6-shuffle epilogue;
//    result lands directly in the (quad,r) layout o needs. Normalizing by
//    the sum of bf16-rounded P = exact convex combination (numerics >=).
//  - P b64->b128 writes via key-position permutation: P col i*16+q*4+r
//    stored at position q*16+i*4+r -> 2 iterations combine into one 16B
//    write (8->4 P writes/half). gemm_qkv writes Vt in the SAME within-64-
//    block permuted order (V epilogue: 4x8B stores per 16-t chunk) so the
//    PV contraction stays position-aligned. P/V reads + staging unchanged.
//  - Everything else identical to R6 (32q/wave, role-split vmcnt, swizzle).

typedef __bf16 bf16x8 __attribute__((ext_vector_type(8)));
typedef __bf16 bf16x2 __attribute__((ext_vector_type(2)));
typedef float f32x4 __attribute__((ext_vector_type(4)));
typedef unsigned short u16x8 __attribute__((ext_vector_type(8)));
typedef unsigned short u16x4 __attribute__((ext_vector_type(4)));

#define MFMA16(a, b, c) __builtin_amdgcn_mfma_f32_16x16x32_bf16((a), (b), (c), 0, 0, 0)

__device__ __forceinline__ unsigned short f2bf(float f) {
    unsigned int u = __float_as_uint(f);
    u += 0x7fffu + ((u >> 16) & 1u);   // round-to-nearest-even
    return (unsigned short)(u >> 16);
}
__device__ __forceinline__ float bf2f(unsigned short h) {
    return __uint_as_float(((unsigned int)h) << 16);
}
__device__ __forceinline__ unsigned int pk2bf(float a, float b) {
#if __has_builtin(__builtin_amdgcn_cvt_pk_bf16_f32)
    bf16x2 v = __builtin_amdgcn_cvt_pk_bf16_f32(a, b);
    return __builtin_bit_cast(unsigned int, v);
#else
    return (unsigned int)f2bf(a) | ((unsigned int)f2bf(b) << 16);
#endif
}
__device__ __forceinline__ float fexp2(float x) {
#if __has_builtin(__builtin_amdgcn_exp2f)
    return __builtin_amdgcn_exp2f(x);   // raw v_exp_f32; args bounded +-1.33
#else
    return exp2f(x);
#endif
}
__device__ __forceinline__ bf16x8 ones_bf16x8() {
    u16x8 u;
#pragma unroll
    for (int j = 0; j < 8; ++j) u[j] = 0x3F80;   // bf16 1.0
    return __builtin_bit_cast(bf16x8, u);
}

// async global->LDS, 16B per lane; LDS dest = wave-uniform base + lane*16
__device__ __forceinline__ void gl_lds16(const void* g, void* l) {
    typedef __attribute__((address_space(1))) unsigned int GU;
    typedef __attribute__((address_space(3))) unsigned int LU;
    __builtin_amdgcn_global_load_lds((GU*)(unsigned long long)g,
                                     (LU*)(unsigned int)(unsigned long long)l,
                                     16, 0, 0);
}

__device__ __forceinline__ void wait_vm0() {
    asm volatile("s_waitcnt vmcnt(0)" ::: "memory");
}

// ---------------- K0: fused fp32 -> bf16 convert (x, w_qkv, w_o) ----------
__global__ void cvt3_kernel(const float* __restrict__ x,
                            const float* __restrict__ wqkv,
                            const float* __restrict__ wo,
                            unsigned short* __restrict__ xb,
                            unsigned short* __restrict__ wqkvb,
                            unsigned short* __restrict__ wob) {
    int i = blockIdx.x * 256 + threadIdx.x;
    const float* src;
    unsigned short* dst;
    int off;
    if (i < 1048576) { src = x; dst = xb; off = i; }
    else if (i < 1835008) { src = wqkv; dst = wqkvb; off = i - 1048576; }
    else { src = wo; dst = wob; off = i - 1835008; }
    float4 f = ((const float4*)src)[off];
    u16x4 o;
    o[0] = f2bf(f.x); o[1] = f2bf(f.y); o[2] = f2bf(f.z); o[3] = f2bf(f.w);
    ((u16x4*)dst)[off] = o;
}

// ---------------- K1: qkv GEMM + fused rmsnorm/rope/pack epilogue ----------
// R3 config: 128x128xBK64 single-buffer (m97 structure), 3/CU, XOR swizzle.
// R7: V epilogue writes Vt in within-64-block PERMUTED t-order (position
// p = q*16 + i*4 + r holds t-offset i*16 + q*4 + r) to match attn's b128
// P-write layout.
#define TBS 72
__global__ __launch_bounds__(256, 3) void gemm_qkv(
    const unsigned short* __restrict__ A,    // xb [4096][1024]
    const unsigned short* __restrict__ Bt,   // wqkvb [3072][1024]
    const float* __restrict__ cosb, const float* __restrict__ sinb,  // [T][16]
    const float* __restrict__ qw, const float* __restrict__ kw,      // [64]
    unsigned short* __restrict__ Qb,  // [H][T][64] (pre-scaled)
    unsigned short* __restrict__ Kb,  // [H][T][64]
    unsigned short* __restrict__ Vt)  // [H][64][T] (pre-scaled by 0.5, permuted)
{
    __shared__ unsigned short smem[16384];  // 32 KB
    unsigned short* As0 = smem;             // [128][32]
    unsigned short* As1 = smem + 4096;
    unsigned short* Bs0 = smem + 8192;
    unsigned short* Bs1 = smem + 12288;

    const int tid = threadIdx.x;
    const int wave = tid >> 6, lane = tid & 63;
    const int quad = lane >> 4, l16 = lane & 15;
    const int m0 = blockIdx.x * 128, n0 = blockIdx.y * 128;
    const int wm = (wave >> 1) * 64, wn = (wave & 1) * 64;

    f32x4 acc[4][4];
#pragma unroll
    for (int i = 0; i < 4; ++i)
#pragma unroll
        for (int j = 0; j < 4; ++j) acc[i][j] = (f32x4){0.f, 0.f, 0.f, 0.f};

    const int lrow = lane >> 2;
    const int lcol = ((lane & 3) ^ ((lane >> 3) & 3)) * 8;   // swizzled src chunk
    const int csw  = (quad ^ ((l16 >> 1) & 3)) * 8;          // swizzled read chunk

    for (int k0 = 0; k0 < 1024; k0 += 64) {
        {
            const unsigned short* ab = A + (size_t)(m0 + wave * 16 + lrow) * 1024 + k0 + lcol;
            gl_lds16(ab,              &As0[wave * 512]);
            gl_lds16(ab + 32,         &As1[wave * 512]);
            gl_lds16(ab + 65536,      &As0[2048 + wave * 512]);   // rows +64
            gl_lds16(ab + 65536 + 32, &As1[2048 + wave * 512]);
            const unsigned short* bb = Bt + (size_t)(n0 + wave * 16 + lrow) * 1024 + k0 + lcol;
            gl_lds16(bb,              &Bs0[wave * 512]);
            gl_lds16(bb + 32,         &Bs1[wave * 512]);
            gl_lds16(bb + 65536,      &Bs0[2048 + wave * 512]);
            gl_lds16(bb + 65536 + 32, &Bs1[2048 + wave * 512]);
        }
        __syncthreads();
        {
            bf16x8 af[4], bfr[4];
#pragma unroll
            for (int mt = 0; mt < 4; ++mt)
                af[mt] = *(const bf16x8*)&As0[(wm + mt * 16 + l16) * 32 + csw];
#pragma unroll
            for (int nt = 0; nt < 4; ++nt)
                bfr[nt] = *(const bf16x8*)&Bs0[(wn + nt * 16 + l16) * 32 + csw];
#pragma unroll
            for (int mt = 0; mt < 4; ++mt)
#pragma unroll
                for (int nt = 0; nt < 4; ++nt)
                    acc[mt][nt] = MFMA16(af[mt], bfr[nt], acc[mt][nt]);
        }
        {
            bf16x8 af[4], bfr[4];
#pragma unroll
            for (int mt = 0; mt < 4; ++mt)
                af[mt] = *(const bf16x8*)&As1[(wm + mt * 16 + l16) * 32 + csw];
#pragma unroll
            for (int nt = 0; nt < 4; ++nt)
                bfr[nt] = *(const bf16x8*)&Bs1[(wn + nt * 16 + l16) * 32 + csw];
#pragma unroll
            for (int mt = 0; mt < 4; ++mt)
#pragma unroll
                for (int nt = 0; nt < 4; ++nt)
                    acc[mt][nt] = MFMA16(af[mt], bfr[nt], acc[mt][nt]);
        }
        __syncthreads();
    }

    unsigned short* tbw = smem + wave * 1152;
    const int region = blockIdx.y >> 3;
    const int h = ((blockIdx.y & 7) << 1) + (wave & 1);

    if (region < 2) {
        const float* wgt = region ? kw : qw;
        unsigned short* dst = region ? Kb : Qb;
        const float post = region ? 1.f : 0.17312340490667046f;
        float w[4];
#pragma unroll
        for (int nt = 0; nt < 4; ++nt) w[nt] = wgt[nt * 16 + l16] * post;
#pragma unroll
        for (int mt = 0; mt < 4; ++mt) {
#pragma unroll
            for (int r = 0; r < 4; ++r) {
                const int row = m0 + wm + mt * 16 + quad * 4 + r;
                float ss = 0.f;
#pragma unroll
                for (int nt = 0; nt < 4; ++nt)
                    ss += acc[mt][nt][r] * acc[mt][nt][r];
                ss += __shfl_xor(ss, 1); ss += __shfl_xor(ss, 2);
                ss += __shfl_xor(ss, 4); ss += __shfl_xor(ss, 8);
                const float rn = rsqrtf(ss * (1.f / 64.f) + 1e-6f);
                float val[4];
#pragma unroll
                for (int nt = 0; nt < 4; ++nt)
                    val[nt] = acc[mt][nt][r] * rn * w[nt];
#pragma unroll
                for (int nt = 0; nt < 2; ++nt) {
                    const float prt = __shfl_xor(val[nt], 1);
                    const int p = nt * 8 + (l16 >> 1);
                    const float c = cosb[row * 16 + p];
                    const float s = sinb[row * 16 + p];
                    val[nt] = (l16 & 1) ? (prt * s + val[nt] * c)
                                        : (val[nt] * c - prt * s);
                }
#pragma unroll
                for (int nt = 0; nt < 4; ++nt)
                    tbw[(quad * 4 + r) * TBS + nt * 16 + l16] = f2bf(val[nt]);
            }
            const int t = lane >> 2, dcol = (lane & 3) * 16;
            u16x8 v0 = *(const u16x8*)&tbw[t * TBS + dcol];
            u16x8 v1 = *(const u16x8*)&tbw[t * TBS + dcol + 8];
            const size_t ob = ((size_t)h * 4096 + (m0 + wm + mt * 16 + t)) * 64 + dcol;
            *(u16x8*)&dst[ob] = v0;
            *(u16x8*)&dst[ob + 8] = v1;
        }
    } else {
        // V region: store permuted within each 64-t block:
        //   position p = q*16 + mt*4 + r  holds  t-offset mt*16 + q*4 + r
#pragma unroll
        for (int mt = 0; mt < 4; ++mt) {
#pragma unroll
            for (int nt = 0; nt < 4; ++nt)
#pragma unroll
                for (int r = 0; r < 4; ++r)
                    tbw[(nt * 16 + l16) * 16 + quad * 4 + r] =
                        f2bf(acc[mt][nt][r] * 0.5f);
            const size_t vo = ((size_t)h * 64 + lane) * 4096 + m0 + wm;
#pragma unroll
            for (int q = 0; q < 4; ++q) {
                u16x4 vq = *(const u16x4*)&tbw[lane * 16 + q * 4];
                *(u16x4*)&Vt[vo + q * 16 + mt * 4] = vq;
            }
        }
    }
}

// ---------------- K2: sliding-window flash attention ----------------------
// R7: lsum via ones-MFMA (no scalar adds, no epilogue shfl); P written as
// 2x b128 per group-half in permuted position order (matches permuted Vt).
// R6 base: 4 waves x 32q, 128-key tiles, K dbuf + early-V, role-split
// counted vmcnt + raw barriers, XOR swizzle, dead/clean skip, setprio.
#define PSTR 72  // P row stride (>=64 required; 144 B, 16B-aligned)

template <int MASK>
__device__ __forceinline__ void qk_exp_2g(
    int sb, int qt0w, int quad, int l16, int csw, int rbase,
    const unsigned short* KsA, const unsigned short* KsB,
    unsigned short* Pw, const bf16x8 (&qf)[2][2])
{
    uint2 hold[2];
#pragma unroll
    for (int i = 0; i < 4; ++i) {
        // K-frags read ONCE, feed both query groups (the R6 amortization)
        const bf16x8 kf0 = *(const bf16x8*)&KsA[(rbase + i * 16 + l16) * 32 + csw];
        const bf16x8 kf1 = *(const bf16x8*)&KsB[(rbase + i * 16 + l16) * 32 + csw];
#pragma unroll
        for (int g = 0; g < 2; ++g) {
            f32x4 z = (f32x4){0.f, 0.f, 0.f, 0.f};
            z = MFMA16(kf0, qf[g][0], z);
            z = MFMA16(kf1, qf[g][1], z);
            float p[4];
#pragma unroll
            for (int r = 0; r < 4; ++r) {
                float e = fexp2(z[r]);   // scale pre-folded into Q
                if (MASK) {              // causal + window in one unsigned compare
                    const int s = sb + i * 16 + quad * 4 + r;
                    e = ((unsigned)((qt0w + g * 16 + l16) - s) < 1024u) ? e : 0.f;
                }
                p[r] = e;
            }
            uint2 pk;
            pk.x = pk2bf(p[0], p[1]);
            pk.y = pk2bf(p[2], p[3]);
            // permuted position: key i*16+quad*4+r stored at quad*16+i*4+r
            if (i == 0 || i == 2) {
                hold[g] = pk;
            } else {
                uint4 w4;
                w4.x = hold[g].x; w4.y = hold[g].y; w4.z = pk.x; w4.w = pk.y;
                *(uint4*)&Pw[(g * 16 + l16) * PSTR + quad * 16 + (i == 3 ? 8 : 0)] = w4;
            }
        }
    }
}

__device__ __forceinline__ void pv_acc_2g(
    int quad, int l16, int csw,
    const unsigned short* VsA, const unsigned short* VsB,
    const unsigned short* Pw, f32x4 (&o)[2][4], f32x4 (&ls)[2])
{
    // P read (A-operand) — wave-private, in-order LDS + lgkmcnt suffices
    bf16x8 pf0[2], pf1[2];
#pragma unroll
    for (int g = 0; g < 2; ++g) {
        pf0[g] = *(const bf16x8*)&Pw[(g * 16 + l16) * PSTR + quad * 8];
        pf1[g] = *(const bf16x8*)&Pw[(g * 16 + l16) * PSTR + 32 + quad * 8];
    }
    const bf16x8 ones = ones_bf16x8();
    __builtin_amdgcn_s_setprio(1);
#pragma unroll
    for (int g = 0; g < 2; ++g) {        // lsum on the MFMA pipe
        ls[g] = MFMA16(pf0[g], ones, ls[g]);
        ls[g] = MFMA16(pf1[g], ones, ls[g]);
    }
#pragma unroll
    for (int dt = 0; dt < 4; ++dt) {
        // V-frags read ONCE, feed both query groups
        const bf16x8 vf0 = *(const bf16x8*)&VsA[(dt * 16 + l16) * 32 + csw];
        const bf16x8 vf1 = *(const bf16x8*)&VsB[(dt * 16 + l16) * 32 + csw];
#pragma unroll
        for (int g = 0; g < 2; ++g) {
            o[g][dt] = MFMA16(pf0[g], vf0, o[g][dt]);
            o[g][dt] = MFMA16(pf1[g], vf1, o[g][dt]);
        }
    }
    __builtin_amdgcn_s_setprio(0);
}

__global__ __launch_bounds__(256) void attn_kernel(
    const unsigned short* __restrict__ Qb,  // [H][T][64] (pre-scaled)
    const unsigned short* __restrict__ Kb,  // [H][T][64]
    const unsigned short* __restrict__ Vt,  // [H][64][T] (pre-scaled, permuted)
    unsigned short* __restrict__ att)       // [T][1024]
{
    __shared__ unsigned short KsA[2][4096], KsB[2][4096];   // [128 keys][32 d]
    __shared__ unsigned short Vs0[2048], Vs1[2048];         // positions 0-63
    __shared__ unsigned short Vs2[2048], Vs3[2048];         // positions 64-127
    __shared__ unsigned short P[4][32 * PSTR];

    // swizzle: h-pair = bid&7 (XCD locality); t descending (LPT balance)
    const int bid = blockIdx.x;
    const int h = ((bid & 7) << 1) | ((bid >> 3) & 1);
    const int t0 = (31 - (bid >> 4)) * 128;

    const int tid = threadIdx.x;
    const int wave = tid >> 6, lane = tid & 63;
    const int quad = lane >> 4, l16 = lane & 15;
    const int qt0 = t0 + wave * 32;  // 32 queries per wave
    const int srow = lane >> 2;                              // 0..15
    const int scol = ((lane & 3) ^ ((lane >> 3) & 3)) * 8;   // swizzled src chunk
    const int csw  = (quad ^ ((l16 >> 1) & 3)) * 8;          // swizzled read chunk

    const unsigned short* Qh = Qb + (size_t)h * 4096 * 64;
    const unsigned short* Kh = Kb + (size_t)h * 4096 * 64;
    const unsigned short* Vh = Vt + (size_t)h * 64 * 4096;

    bf16x8 qf[2][2];
#pragma unroll
    for (int g = 0; g < 2; ++g) {
        qf[g][0] = *(const bf16x8*)&Qh[(qt0 + g * 16 + l16) * 64 + quad * 8];
        qf[g][1] = *(const bf16x8*)&Qh[(qt0 + g * 16 + l16) * 64 + 32 + quad * 8];
    }

    f32x4 o[2][4];
    f32x4 ls[2];
#pragma unroll
    for (int g = 0; g < 2; ++g) {
        ls[g] = (f32x4){0.f, 0.f, 0.f, 0.f};
#pragma unroll
        for (int dt = 0; dt < 4; ++dt) o[g][dt] = (f32x4){0.f, 0.f, 0.f, 0.f};
    }
    unsigned short* Pw = P[wave];

    // staging: waves 0-1 stage K (8 gl_lds each), waves 2-3 stage V (8 each)
    auto stageK = [&](int b, int s) {
        if (wave < 2) {
#pragma unroll
            for (int l = 0; l < 4; ++l) {
                const int rg = wave * 4 + l;   // row-group 0..7 (16 rows each)
                const unsigned short* kb =
                    Kh + (size_t)(s + rg * 16 + srow) * 64 + scol;
                gl_lds16(kb,      &KsA[b][rg * 512]);
                gl_lds16(kb + 32, &KsB[b][rg * 512]);
            }
        }
    };
    auto stageV = [&](int s) {
        if (wave >= 2) {
            const int w2 = wave - 2;
#pragma unroll
            for (int l = 0; l < 2; ++l) {
                const int dg = w2 * 2 + l;     // d-group 0..3 (16 d-rows each)
                const unsigned short* vb =
                    Vh + (size_t)(dg * 16 + srow) * 4096 + s + scol;
                gl_lds16(vb,      &Vs0[dg * 512]);
                gl_lds16(vb + 32, &Vs1[dg * 512]);
                gl_lds16(vb + 64, &Vs2[dg * 512]);
                gl_lds16(vb + 96, &Vs3[dg * 512]);
            }
        }
    };

    const int s_lo = (t0 >= 1024) ? (t0 - 1024) : 0;
    const int NT = ((t0 - s_lo) >> 7) + 1;   // 128-key tiles

    stageK(0, s_lo);
    if (wave < 2) wait_vm0();      // only K-staging waves have loads in flight
    __builtin_amdgcn_s_barrier();  // publish K(0)
    __builtin_amdgcn_sched_barrier(0);
    int buf = 0;
    for (int n = 0; n < NT; ++n) {
        const int s0 = s_lo + n * 128;
        const int sb1 = s0 + 64;
        if (n + 1 < NT) stageK(buf ^ 1, s0 + 128);   // in flight across barrier1
        stageV(s0);                                  // drained at barrier1
        // per-half, per-wave classification (wave-uniform; 32q: qlo..qlo+31)
        const bool d0 = (s0 + 63 < qt0 - 1023);      // h0 never future-dead
        const bool c0 = (s0 + 63 <= qt0) && (s0 >= qt0 - 992);
        const bool d1 = (sb1 > qt0 + 31) || (sb1 + 63 < qt0 - 1023);
        const bool c1 = (sb1 + 63 <= qt0) && (sb1 >= qt0 - 992);
        if (!d0) {
            if (c0) qk_exp_2g<0>(s0, qt0, quad, l16, csw, 0, KsA[buf], KsB[buf],
                                 Pw, qf);
            else    qk_exp_2g<1>(s0, qt0, quad, l16, csw, 0, KsA[buf], KsB[buf],
                                 Pw, qf);
        }
        if (wave >= 2) wait_vm0();     // V(n) done; K(n+1) stays in flight
        __builtin_amdgcn_s_barrier();  // publish V(n)
        __builtin_amdgcn_sched_barrier(0);
        if (!d0) pv_acc_2g(quad, l16, csw, Vs0, Vs1, Pw, o, ls);
        if (!d1) {
            if (c1) qk_exp_2g<0>(sb1, qt0, quad, l16, csw, 64, KsA[buf], KsB[buf],
                                 Pw, qf);
            else    qk_exp_2g<1>(sb1, qt0, quad, l16, csw, 64, KsA[buf], KsB[buf],
                                 Pw, qf);
            pv_acc_2g(quad, l16, csw, Vs2, Vs3, Pw, o, ls);
        }
        if (wave < 2) wait_vm0();      // K(n+1) done (covered by full tile)
        __builtin_amdgcn_s_barrier();  // publish K(n+1); protect Vs/Ks reuse
        __builtin_amdgcn_sched_barrier(0);
        buf ^= 1;
    }

#pragma unroll
    for (int g = 0; g < 2; ++g) {
        float lr[4];
#pragma unroll
        for (int r = 0; r < 4; ++r) lr[r] = 1.f / ls[g][r];
#pragma unroll
        for (int dt = 0; dt < 4; ++dt)
#pragma unroll
            for (int r = 0; r < 4; ++r)
                att[(size_t)(qt0 + g * 16 + quad * 4 + r) * 1024 +
                    h * 64 + dt * 16 + l16] = f2bf(o[g][dt][r] * lr[r]);
    }
}

// ---------------- K3: output GEMM (BM=64, BN=128, BK=64, prefetch-dbuf) ---
// Session-measured-best config (512 blocks, 2/CU supply-starved regime:
// dbuf is the measured win there). + R2 XOR bank-swizzle.
__global__ __launch_bounds__(256) void gemm_out(
    const unsigned short* __restrict__ A,    // attb [4096][1024]
    const unsigned short* __restrict__ Bt,   // wob  [1024][1024]
    float* __restrict__ C)                   // [4096][1024]
{
    __shared__ unsigned short As0[2][2048], As1[2][2048];
    __shared__ unsigned short Bs0[2][4096], Bs1[2][4096];
    const int tid = threadIdx.x;
    const int wave = tid >> 6, lane = tid & 63;
    const int quad = lane >> 4, l16 = lane & 15;
    const int m0 = blockIdx.x * 64, n0 = blockIdx.y * 128;
    const int wm = (wave >> 1) * 32, wn = (wave & 1) * 64;
    const int lrow = lane >> 2;
    const int lcol = ((lane & 3) ^ ((lane >> 3) & 3)) * 8;   // swizzled src chunk
    const int csw  = (quad ^ ((l16 >> 1) & 3)) * 8;          // swizzled read chunk

    f32x4 acc[2][4];
#pragma unroll
    for (int i = 0; i < 2; ++i)
#pragma unroll
        for (int j = 0; j < 4; ++j) acc[i][j] = (f32x4){0.f, 0.f, 0.f, 0.f};

    auto stage = [&](int buf, int k0) {
        const unsigned short* ab = A + (size_t)(m0 + wave * 16 + lrow) * 1024 + k0 + lcol;
        gl_lds16(ab,      &As0[buf][wave * 512]);
        gl_lds16(ab + 32, &As1[buf][wave * 512]);
#pragma unroll
        for (int i = 0; i < 2; ++i) {
            const int c = wave * 2 + i;
            const unsigned short* bb = Bt + (size_t)(n0 + c * 16 + lrow) * 1024 + k0 + lcol;
            gl_lds16(bb,      &Bs0[buf][c * 512]);
            gl_lds16(bb + 32, &Bs1[buf][c * 512]);
        }
    };

    stage(0, 0);
    __syncthreads();
    int buf = 0;
    for (int k0 = 0; k0 < 1024; k0 += 64) {
        if (k0 + 64 < 1024) stage(buf ^ 1, k0 + 64);  // prefetch before compute
        {
            bf16x8 af[2], bfr[4];
#pragma unroll
            for (int mt = 0; mt < 2; ++mt)
                af[mt] = *(const bf16x8*)&As0[buf][(wm + mt * 16 + l16) * 32 + csw];
#pragma unroll
            for (int nt = 0; nt < 4; ++nt)
                bfr[nt] = *(const bf16x8*)&Bs0[buf][(wn + nt * 16 + l16) * 32 + csw];
#pragma unroll
            for (int mt = 0; mt < 2; ++mt)
#pragma unroll
                for (int nt = 0; nt < 4; ++nt)
                    acc[mt][nt] = MFMA16(af[mt], bfr[nt], acc[mt][nt]);
        }
        {
            bf16x8 af[2], bfr[4];
#pragma unroll
            for (int mt = 0; mt < 2; ++mt)
                af[mt] = *(const bf16x8*)&As1[buf][(wm + mt * 16 + l16) * 32 + csw];
#pragma unroll
            for (int nt = 0; nt < 4; ++nt)
                bfr[nt] = *(const bf16x8*)&Bs1[buf][(wn + nt * 16 + l16) * 32 + csw];
#pragma unroll
            for (int mt = 0; mt < 2; ++mt)
#pragma unroll
                for (int nt = 0; nt < 4; ++nt)
                    acc[mt][nt] = MFMA16(af[mt], bfr[nt], acc[mt][nt]);
        }
        __syncthreads();  // publishes prefetched tiles; protects buf reuse
        buf ^= 1;
    }
#pragma unroll
    for (int mt = 0; mt < 2; ++mt)
#pragma unroll
        for (int nt = 0; nt < 4; ++nt)
#pragma unroll
            for (int r = 0; r < 4; ++r) {
                const int row = m0 + wm + mt * 16 + quad * 4 + r;
                const int col = n0 + wn + nt * 16 + l16;
                C[(size_t)row * 1024 + col] = acc[mt][nt][r];
            }
}

// ---------------- launcher ----------------
extern "C" void kernel_launch(void* const* d_in, const int* in_sizes, int n_in,
                              void* d_out, int out_size, void* d_ws, size_t ws_size,
                              hipStream_t stream) {
    const float* x    = (const float*)d_in[0];
    const float* wqkv = (const float*)d_in[3];
    const float* wo   = (const float*)d_in[4];
    const float* qw   = (const float*)d_in[5];
    const float* kw   = (const float*)d_in[6];
    const float* cosb = (const float*)d_in[7];
    const float* sinb = (const float*)d_in[8];

    char* ws = (char*)d_ws;
    // ws (MiB): xb 0-8 | wqkvb 8-14 | wob 14-16 | Qb 16-24 | Kb 24-32
    //           Vt 32-40 | attb 40-48
    if (ws_size < (size_t)48 * 1024 * 1024) return;
    unsigned short* xb    = (unsigned short*)(ws + ((size_t)0 << 20));
    unsigned short* wqkvb = (unsigned short*)(ws + ((size_t)8 << 20));
    unsigned short* wob   = (unsigned short*)(ws + ((size_t)14 << 20));
    unsigned short* Qb    = (unsigned short*)(ws + ((size_t)16 << 20));
    unsigned short* Kb    = (unsigned short*)(ws + ((size_t)24 << 20));
    unsigned short* Vt    = (unsigned short*)(ws + ((size_t)32 << 20));
    unsigned short* attb  = (unsigned short*)(ws + ((size_t)40 << 20));

    // K0: fused converts (one launch)
    cvt3_kernel<<<8192, 256, 0, stream>>>(x, wqkv, wo, xb, wqkvb, wob);

    // K1: qkv GEMM + fused rmsnorm/rope/pack epilogue (128x128x64, 3/CU)
    gemm_qkv<<<dim3(32, 24), 256, 0, stream>>>(xb, wqkvb, cosb, sinb, qw, kw,
                                               Qb, Kb, Vt);

    // K2: sliding-window attention (ones-MFMA lsum, b128 P writes)
    attn_kernel<<<512, 256, 0, stream>>>(Qb, Kb, Vt, attb);

    // K3: y = att @ w_o^T  (M=4096, N=1024, K=1024), fp32 out, BK64 dbuf
    gemm_out<<<dim3(64, 8), 256, 0, stream>>>(attb, wob, (float*)d_out);
}